// Round 2
// baseline (2261.804 us; speedup 1.0000x reference)
//
#include <hip/hip_runtime.h>
#include <cstdint>

typedef __attribute__((ext_vector_type(4))) float f32x4;
typedef __attribute__((ext_vector_type(8))) short short8;
typedef _Float16 half8v __attribute__((ext_vector_type(8)));

// f32 -> f16 bits (RTE via hardware cvt)
__device__ __forceinline__ unsigned short f2h(float x) {
  _Float16 h = (_Float16)x;
  return __builtin_bit_cast(unsigned short, h);
}

// ---- MFMA wrapper: tolerant of short8-vs-half8 builtin signatures ----
template <typename V>
__device__ __forceinline__ auto mfma_impl(V a, V b, f32x4 c, int)
    -> decltype(__builtin_amdgcn_mfma_f32_16x16x32_f16(a, b, c, 0, 0, 0)) {
  return __builtin_amdgcn_mfma_f32_16x16x32_f16(a, b, c, 0, 0, 0);
}
template <typename V>
__device__ __forceinline__ f32x4 mfma_impl(V a, V b, f32x4 c, long) {
  return __builtin_amdgcn_mfma_f32_16x16x32_f16(
      __builtin_bit_cast(half8v, a), __builtin_bit_cast(half8v, b), c, 0, 0, 0);
}
__device__ __forceinline__ f32x4 MFMA(short8 a, short8 b, f32x4 c) {
  return mfma_impl(a, b, c, 0);
}

// ---- async global->LDS, 16B per lane, wave-uniform LDS base ----
__device__ __forceinline__ void load_lds16(const void* g, void* l) {
  __builtin_amdgcn_global_load_lds(
      (__attribute__((address_space(1))) void*)(uintptr_t)g,
      (__attribute__((address_space(3))) void*)l, 16, 0, 0);
}

// ============================ LayerNorm -> f16 =============================
__global__ __launch_bounds__(256) void ln_f16_kernel(
    const float* __restrict__ X, const float* __restrict__ gam,
    const float* __restrict__ bet, unsigned short* __restrict__ Y) {
  __shared__ float red[8];
  const int row = blockIdx.x, t = threadIdx.x;
  const float4 v = ((const float4*)(X + (size_t)row * 1024))[t];
  float s = v.x + v.y + v.z + v.w;
#pragma unroll
  for (int o = 32; o >= 1; o >>= 1) s += __shfl_xor(s, o, 64);
  if ((t & 63) == 0) red[t >> 6] = s;
  __syncthreads();
  const float mean = (red[0] + red[1] + red[2] + red[3]) * (1.0f / 1024.0f);
  const float dx = v.x - mean, dy = v.y - mean, dz = v.z - mean, dw = v.w - mean;
  float ss = dx * dx + dy * dy + dz * dz + dw * dw;
#pragma unroll
  for (int o = 32; o >= 1; o >>= 1) ss += __shfl_xor(ss, o, 64);
  if ((t & 63) == 0) red[4 + (t >> 6)] = ss;
  __syncthreads();
  const float var = (red[4] + red[5] + red[6] + red[7]) * (1.0f / 1024.0f);
  const float rstd = rsqrtf(var + 1e-5f);
  const float4 gg = ((const float4*)gam)[t];
  const float4 bb = ((const float4*)bet)[t];
  ushort4 o4;
  o4.x = f2h(dx * rstd * gg.x + bb.x);
  o4.y = f2h(dy * rstd * gg.y + bb.y);
  o4.z = f2h(dz * rstd * gg.z + bb.z);
  o4.w = f2h(dw * rstd * gg.w + bb.w);
  ((ushort4*)(Y + (size_t)row * 1024))[t] = o4;
}

// ================= transpose + fp32->f16 convert: W[K][N] -> WT[N][K] ======
__global__ __launch_bounds__(256) void transpose_f16_kernel(
    const float* __restrict__ W, unsigned short* __restrict__ WT, int K, int N) {
  __shared__ float t[32][33];
  const int n0 = blockIdx.x * 32, k0 = blockIdx.y * 32;
  const int tx = threadIdx.x, ty = threadIdx.y;
#pragma unroll
  for (int i = 0; i < 4; ++i)
    t[ty + 8 * i][tx] = W[(size_t)(k0 + ty + 8 * i) * N + n0 + tx];
  __syncthreads();
#pragma unroll
  for (int i = 0; i < 4; ++i)
    WT[(size_t)(n0 + ty + 8 * i) * K + k0 + tx] = f2h(t[tx][ty + 8 * i]);
}

// ============================ GEMM (f16 MFMA) ==============================
// C[M][N] = A[M][K] @ B[K][N], B given transposed (BT[N][K]).
// EPI 0: f16 store. EPI 1: f16 store of gelu(acc+bias). EPI 2: f32 store of
// res + acc + bias (residual update in place).
template <int EPI>
__global__ __launch_bounds__(256) void gemm_f16_kernel(
    const unsigned short* __restrict__ A, const unsigned short* __restrict__ BT,
    void* Cout, const float* __restrict__ bias, const float* res,
    int M, int N, int K) {
  __shared__ unsigned short a_sh[128 * 32];
  __shared__ unsigned short b_sh[128 * 32];
  const int tid = threadIdx.x;
  const int w = tid >> 6, lane = tid & 63;
  const int g = lane >> 4, lm = lane & 15;
  const int m0 = blockIdx.y * 128, n0 = blockIdx.x * 128;
  const int wm = (w >> 1) * 64, wn = (w & 1) * 64;
  f32x4 acc[4][4] = {};

  for (int kk = 0; kk < K; kk += 32) {
    __syncthreads();  // protect LDS from previous iteration's readers
#pragma unroll
    for (int s = 0; s < 2; ++s) {
      const int cbase = s * 256 + w * 64;
      const int c = cbase + lane;  // 16B chunk id in [0,512)
      const int r = c >> 2, cc = c & 3;
      load_lds16(A + (size_t)(m0 + r) * K + kk + cc * 8, a_sh + cbase * 8);
      load_lds16(BT + (size_t)(n0 + r) * K + kk + cc * 8, b_sh + cbase * 8);
    }
    __syncthreads();
    short8 af[4], bf[4];
#pragma unroll
    for (int i = 0; i < 4; ++i)
      af[i] = *(const short8*)&a_sh[(wm + i * 16 + lm) * 32 + g * 8];
#pragma unroll
    for (int j = 0; j < 4; ++j)
      bf[j] = *(const short8*)&b_sh[(wn + j * 16 + lm) * 32 + g * 8];
#pragma unroll
    for (int i = 0; i < 4; ++i)
#pragma unroll
      for (int j = 0; j < 4; ++j)
        acc[i][j] = MFMA(af[i], bf[j], acc[i][j]);
  }

#pragma unroll
  for (int i = 0; i < 4; ++i) {
    const int row = m0 + wm + i * 16 + g * 4;
#pragma unroll
    for (int j = 0; j < 4; ++j) {
      const int col = n0 + wn + j * 16 + lm;
#pragma unroll
      for (int r = 0; r < 4; ++r) {
        const float v = acc[i][j][r];
        const size_t idx = (size_t)(row + r) * N + col;
        if (EPI == 0) {
          ((unsigned short*)Cout)[idx] = f2h(v);
        } else if (EPI == 1) {
          const float xx = v + bias[col];
          ((unsigned short*)Cout)[idx] =
              f2h(0.5f * xx * (1.0f + erff(xx * 0.70710678118654752f)));
        } else {
          ((float*)Cout)[idx] = res[idx] + v + bias[col];
        }
      }
    }
  }
}

// ============================ Flash attention ==============================
// qkv f16 [4096][3072] (Q|K|V per 1024 cols). Computes S^T = K Q^T per tile,
// online softmax (unscaled logits), O^T = V^T P^T, output *8 (the /SCALE).
__global__ __launch_bounds__(256) void attn_kernel(
    const unsigned short* __restrict__ qkv, unsigned short* __restrict__ obuf) {
  constexpr int P = 72;  // LDS row pitch (f16 elems), 144B = 9*16B
  __shared__ unsigned short Qs[64 * P], Ks[64 * P], Vs[64 * P];
  const int tid = threadIdx.x;
  const int w = tid >> 6, lane = tid & 63;
  const int g = lane >> 4, lm = lane & 15;
  const int qbase = blockIdx.x * 64, h = blockIdx.y, b = blockIdx.z;
  const size_t rowbase = (size_t)b * 2048;

  // stage Q tile: 64 rows x 64 cols
#pragma unroll
  for (int s = 0; s < 2; ++s) {
    const int c = s * 256 + tid;
    const int r = c >> 3, cc = c & 7;
    *(uint4*)&Qs[r * P + cc * 8] =
        *(const uint4*)(qkv + (rowbase + qbase + r) * 3072 + h * 64 + cc * 8);
  }

  float mrun = -1e30f, lrun = 0.0f;
  f32x4 accO[4] = {};  // O^T dh-tiles

  for (int kv0 = 0; kv0 < 2048; kv0 += 64) {
    __syncthreads();
#pragma unroll
    for (int s = 0; s < 2; ++s) {
      const int c = s * 256 + tid;
      const int r = c >> 3, cc = c & 7;
      const size_t grow = (rowbase + kv0 + r) * 3072 + h * 64 + cc * 8;
      *(uint4*)&Ks[r * P + cc * 8] = *(const uint4*)(qkv + 1024 + grow);
      *(uint4*)&Vs[r * P + cc * 8] = *(const uint4*)(qkv + 2048 + grow);
    }
    __syncthreads();

    // S^T tiles: rows kv (4 subtiles of 16), cols q (this wave's 16 rows)
    f32x4 sf[4];
#pragma unroll
    for (int i = 0; i < 4; ++i) sf[i] = f32x4{0.f, 0.f, 0.f, 0.f};
#pragma unroll
    for (int step = 0; step < 2; ++step) {
      const short8 qf = *(const short8*)&Qs[(w * 16 + lm) * P + step * 32 + g * 8];
#pragma unroll
      for (int i = 0; i < 4; ++i) {
        const short8 kf = *(const short8*)&Ks[(i * 16 + lm) * P + step * 32 + g * 8];
        sf[i] = MFMA(kf, qf, sf[i]);
      }
    }

    // online softmax per q (= lm); lanes lm, lm+16, lm+32, lm+48 share a row
    float tmax = -1e30f;
#pragma unroll
    for (int i = 0; i < 4; ++i)
#pragma unroll
      for (int r = 0; r < 4; ++r) tmax = fmaxf(tmax, sf[i][r]);
    tmax = fmaxf(tmax, __shfl_xor(tmax, 16, 64));
    tmax = fmaxf(tmax, __shfl_xor(tmax, 32, 64));
    const float mnew = fmaxf(mrun, tmax);
    const float scale = __expf(mrun - mnew);
    float p[4][4];
    float psum = 0.0f;
#pragma unroll
    for (int i = 0; i < 4; ++i)
#pragma unroll
      for (int r = 0; r < 4; ++r) {
        p[i][r] = __expf(sf[i][r] - mnew);
        psum += p[i][r];
      }
    psum += __shfl_xor(psum, 16, 64);
    psum += __shfl_xor(psum, 32, 64);
    lrun = lrun * scale + psum;
    mrun = mnew;
#pragma unroll
    for (int t = 0; t < 4; ++t) accO[t] = accO[t] * scale;

    // pack P -> f16 B-operand frags (kv slot mapping mirrors V^T A-operand)
    short8 pb[2];
#pragma unroll
    for (int blk = 0; blk < 2; ++blk)
#pragma unroll
      for (int j = 0; j < 8; ++j)
        pb[blk][j] = (short)f2h(p[2 * blk + (j >> 2)][j & 3]);

    // O^T += V^T @ P^T
#pragma unroll
    for (int blk = 0; blk < 2; ++blk) {
#pragma unroll
      for (int t = 0; t < 4; ++t) {
        short8 vf;
#pragma unroll
        for (int j = 0; j < 8; ++j) {
          const int kvl = 32 * blk + ((j >> 2) << 4) + 4 * g + (j & 3);
          vf[j] = (short)Vs[kvl * P + t * 16 + lm];
        }
        accO[t] = MFMA(vf, pb[blk], accO[t]);
      }
    }
  }

  // epilogue: divide by row-sum, multiply by 1/SCALE = 8
  const float inv = 8.0f / lrun;
  const size_t orow = rowbase + qbase + w * 16 + lm;
#pragma unroll
  for (int t = 0; t < 4; ++t)
#pragma unroll
    for (int r = 0; r < 4; ++r) {
      const int col = h * 64 + t * 16 + g * 4 + r;
      obuf[orow * 1024 + col] = f2h(accO[t][r] * inv);
    }
}

// ================================ driver ===================================
extern "C" void kernel_launch(void* const* d_in, const int* in_sizes, int n_in,
                              void* d_out, int out_size, void* d_ws, size_t ws_size,
                              hipStream_t stream) {
  const float* x     = (const float*)d_in[0];
  const float* ln1_g = (const float*)d_in[1];
  const float* ln1_b = (const float*)d_in[2];
  const float* w_qkv = (const float*)d_in[3];
  const float* w_out = (const float*)d_in[4];
  const float* b_out = (const float*)d_in[5];
  const float* ln2_g = (const float*)d_in[6];
  const float* ln2_b = (const float*)d_in[7];
  const float* w1    = (const float*)d_in[8];
  const float* b1    = (const float*)d_in[9];
  const float* w2    = (const float*)d_in[10];
  const float* b2    = (const float*)d_in[11];
  float* h = (float*)d_out;  // residual stream lives in d_out

  char* ws = (char*)d_ws;
  const size_t MB = 1u << 20;
  unsigned short* xn   = (unsigned short*)(ws);             //  8 MiB
  unsigned short* ob   = (unsigned short*)(ws + 8 * MB);    //  8 MiB
  unsigned short* qkvb = (unsigned short*)(ws + 16 * MB);   // 24 MiB
  unsigned short* mid  = (unsigned short*)(ws + 40 * MB);   // 32 MiB
  unsigned short* wt   = (unsigned short*)(ws + 72 * MB);   //  8 MiB

  hipMemcpyAsync(h, x, (size_t)4096 * 1024 * sizeof(float),
                 hipMemcpyDeviceToDevice, stream);

  const dim3 tb(32, 8);
  for (int L = 0; L < 6; ++L) {
    const float* Lg1 = ln1_g + L * 1024;
    const float* Lb1 = ln1_b + L * 1024;
    const float* Lwq = w_qkv + (size_t)L * 1024 * 3072;
    const float* Lwo = w_out + (size_t)L * 1024 * 1024;
    const float* Lbo = b_out + L * 1024;
    const float* Lg2 = ln2_g + L * 1024;
    const float* Lb2 = ln2_b + L * 1024;
    const float* Lw1 = w1 + (size_t)L * 1024 * 4096;
    const float* Lb1m = b1 + L * 4096;
    const float* Lw2 = w2 + (size_t)L * 4096 * 1024;
    const float* Lb2m = b2 + L * 1024;

    // --- attention path ---
    ln_f16_kernel<<<4096, 256, 0, stream>>>(h, Lg1, Lb1, xn);
    transpose_f16_kernel<<<dim3(96, 32), tb, 0, stream>>>(Lwq, wt, 1024, 3072);
    gemm_f16_kernel<0><<<dim3(24, 32), 256, 0, stream>>>(
        xn, wt, qkvb, nullptr, nullptr, 4096, 3072, 1024);
    attn_kernel<<<dim3(32, 16, 2), 256, 0, stream>>>(qkvb, ob);
    transpose_f16_kernel<<<dim3(32, 32), tb, 0, stream>>>(Lwo, wt, 1024, 1024);
    gemm_f16_kernel<2><<<dim3(8, 32), 256, 0, stream>>>(
        ob, wt, h, Lbo, h, 4096, 1024, 1024);

    // --- MLP path ---
    ln_f16_kernel<<<4096, 256, 0, stream>>>(h, Lg2, Lb2, xn);
    transpose_f16_kernel<<<dim3(128, 32), tb, 0, stream>>>(Lw1, wt, 1024, 4096);
    gemm_f16_kernel<1><<<dim3(32, 32), 256, 0, stream>>>(
        xn, wt, mid, Lb1m, nullptr, 4096, 4096, 1024);
    transpose_f16_kernel<<<dim3(32, 128), tb, 0, stream>>>(Lw2, wt, 4096, 1024);
    gemm_f16_kernel<2><<<dim3(8, 32), 256, 0, stream>>>(
        mid, wt, h, Lb2m, h, 4096, 1024, 4096);
  }
  (void)in_sizes; (void)n_in; (void)out_size; (void)ws_size;
}

// Round 5
// 1853.484 us; speedup vs baseline: 1.2203x; 1.2203x over previous
//
#include <hip/hip_runtime.h>
#include <cstdint>

typedef __attribute__((ext_vector_type(4))) float f32x4;
typedef __attribute__((ext_vector_type(8))) short short8;
typedef _Float16 half8v __attribute__((ext_vector_type(8)));

// f32 -> f16 bits (RTE via hardware cvt)
__device__ __forceinline__ unsigned short f2h(float x) {
  _Float16 h = (_Float16)x;
  return __builtin_bit_cast(unsigned short, h);
}

// ---- MFMA wrapper: tolerant of short8-vs-half8 builtin signatures ----
template <typename V>
__device__ __forceinline__ auto mfma_impl(V a, V b, f32x4 c, int)
    -> decltype(__builtin_amdgcn_mfma_f32_16x16x32_f16(a, b, c, 0, 0, 0)) {
  return __builtin_amdgcn_mfma_f32_16x16x32_f16(a, b, c, 0, 0, 0);
}
template <typename V>
__device__ __forceinline__ f32x4 mfma_impl(V a, V b, f32x4 c, long) {
  return __builtin_amdgcn_mfma_f32_16x16x32_f16(
      __builtin_bit_cast(half8v, a), __builtin_bit_cast(half8v, b), c, 0, 0, 0);
}
__device__ __forceinline__ f32x4 MFMA(short8 a, short8 b, f32x4 c) {
  return mfma_impl(a, b, c, 0);
}

// ---- async global->LDS, 16B per lane, LDS dest MUST be wave-uniform ----
__device__ __forceinline__ void load_lds16(const void* g, void* l) {
  __builtin_amdgcn_global_load_lds(
      (__attribute__((address_space(1))) void*)(uintptr_t)g,
      (__attribute__((address_space(3))) void*)l, 16, 0, 0);
}

// ============================ LayerNorm -> f16 =============================
__global__ __launch_bounds__(256) void ln_f16_kernel(
    const float* __restrict__ X, const float* __restrict__ gam,
    const float* __restrict__ bet, unsigned short* __restrict__ Y) {
  __shared__ float red[8];
  const int row = blockIdx.x, t = threadIdx.x;
  const float4 v = ((const float4*)(X + (size_t)row * 1024))[t];
  float s = v.x + v.y + v.z + v.w;
#pragma unroll
  for (int o = 32; o >= 1; o >>= 1) s += __shfl_xor(s, o, 64);
  if ((t & 63) == 0) red[t >> 6] = s;
  __syncthreads();
  const float mean = (red[0] + red[1] + red[2] + red[3]) * (1.0f / 1024.0f);
  const float dx = v.x - mean, dy = v.y - mean, dz = v.z - mean, dw = v.w - mean;
  float ss = dx * dx + dy * dy + dz * dz + dw * dw;
#pragma unroll
  for (int o = 32; o >= 1; o >>= 1) ss += __shfl_xor(ss, o, 64);
  if ((t & 63) == 0) red[4 + (t >> 6)] = ss;
  __syncthreads();
  const float var = (red[4] + red[5] + red[6] + red[7]) * (1.0f / 1024.0f);
  const float rstd = rsqrtf(var + 1e-5f);
  const float4 gg = ((const float4*)gam)[t];
  const float4 bb = ((const float4*)bet)[t];
  ushort4 o4;
  o4.x = f2h(dx * rstd * gg.x + bb.x);
  o4.y = f2h(dy * rstd * gg.y + bb.y);
  o4.z = f2h(dz * rstd * gg.z + bb.z);
  o4.w = f2h(dw * rstd * gg.w + bb.w);
  ((ushort4*)(Y + (size_t)row * 1024))[t] = o4;
}

// ================= transpose + fp32->f16 convert: W[K][N] -> WT[N][K] ======
__global__ __launch_bounds__(256) void transpose_f16_kernel(
    const float* __restrict__ W, unsigned short* __restrict__ WT, int K, int N) {
  __shared__ float t[32][33];
  const int n0 = blockIdx.x * 32, k0 = blockIdx.y * 32;
  const int tx = threadIdx.x, ty = threadIdx.y;
#pragma unroll
  for (int i = 0; i < 4; ++i)
    t[ty + 8 * i][tx] = W[(size_t)(k0 + ty + 8 * i) * N + n0 + tx];
  __syncthreads();
#pragma unroll
  for (int i = 0; i < 4; ++i)
    WT[(size_t)(n0 + ty + 8 * i) * K + k0 + tx] = f2h(t[tx][ty + 8 * i]);
}

// ============================ GEMM (f16 MFMA) ==============================
// C[M][N] = A[M][K] @ B[K][N] with BT[N][K]. BK=64, double-buffered LDS,
// 2-phase pipeline (stage next || compute current), XOR-swizzled LDS layout
// (pre-swizzled per-lane global SOURCE; wave-uniform linear LDS dest;
// swizzled reads). EPI 0: f16. EPI 1: f16 gelu(acc+bias). EPI 2: f32 res+acc+bias.
template <int BM, int EPI>
__global__ __launch_bounds__(256, BM == 64 ? 3 : 2) void gemm_f16_kernel(
    const unsigned short* __restrict__ A, const unsigned short* __restrict__ BT,
    void* Cout, const float* __restrict__ bias, const float* __restrict__ res,
    int M, int N, int K) {
  constexpr int BN = 128, BK = 64;
  constexpr int MR = BM / 32;             // frag-rows per wave (wave = BM/2 x 64)
  constexpr int ACH = BM * BK / 8;        // 16B chunks of A per K-step
  constexpr int BCH = BN * BK / 8;
  __shared__ alignas(16) unsigned short a_sh[2][BM * BK];
  __shared__ alignas(16) unsigned short b_sh[2][BN * BK];
  const int tid = threadIdx.x;
  const int w = tid >> 6, lane = tid & 63, g = lane >> 4, lm = lane & 15;
  const int m0 = blockIdx.y * BM, n0 = blockIdx.x * BN;
  const int wm = (w >> 1) * (BM / 2), wn = (w & 1) * 64;
  f32x4 acc[MR][4] = {};
  const int nsteps = K >> 6;

  auto stage = [&](int buf, int kk) {
#pragma unroll
    for (int c0 = 0; c0 < ACH; c0 += 256) {
      const int c = c0 + tid, row = c >> 3;
      const int sc = (c & 7) ^ (row & 7);   // pre-swizzled per-lane source
      const int cb = c0 + (tid & 192);      // wave-uniform dest chunk base
      load_lds16(A + (size_t)(m0 + row) * K + kk + sc * 8, &a_sh[buf][cb * 8]);
    }
#pragma unroll
    for (int c0 = 0; c0 < BCH; c0 += 256) {
      const int c = c0 + tid, row = c >> 3;
      const int sc = (c & 7) ^ (row & 7);
      const int cb = c0 + (tid & 192);
      load_lds16(BT + (size_t)(n0 + row) * K + kk + sc * 8, &b_sh[buf][cb * 8]);
    }
  };

  stage(0, 0);
  __syncthreads();
  int cur = 0;
  for (int step = 0; step < nsteps; ++step) {
    if (step + 1 < nsteps) stage(cur ^ 1, (step + 1) * BK);
#pragma unroll
    for (int kc = 0; kc < 2; ++kc) {
      short8 af[MR], bfr[4];
#pragma unroll
      for (int i = 0; i < MR; ++i) {
        const int r = wm + i * 16 + lm;
        af[i] = *(const short8*)&a_sh[cur][r * 64 + (((kc << 2) | g) ^ (r & 7)) * 8];
      }
#pragma unroll
      for (int j = 0; j < 4; ++j) {
        const int r = wn + j * 16 + lm;
        bfr[j] = *(const short8*)&b_sh[cur][r * 64 + (((kc << 2) | g) ^ (r & 7)) * 8];
      }
#pragma unroll
      for (int i = 0; i < MR; ++i)
#pragma unroll
        for (int j = 0; j < 4; ++j)
          acc[i][j] = MFMA(af[i], bfr[j], acc[i][j]);
    }
    if (step + 1 < nsteps) {
      __syncthreads();  // drains prefetch vmcnt + LDS reads; swap buffers
      cur ^= 1;
    }
  }

#pragma unroll
  for (int i = 0; i < MR; ++i) {
    const int row = m0 + wm + i * 16 + g * 4;
#pragma unroll
    for (int j = 0; j < 4; ++j) {
      const int col = n0 + wn + j * 16 + lm;
#pragma unroll
      for (int r = 0; r < 4; ++r) {
        const float v = acc[i][j][r];
        const size_t idx = (size_t)(row + r) * N + col;
        if (EPI == 0) {
          ((unsigned short*)Cout)[idx] = f2h(v);
        } else if (EPI == 1) {
          const float xx = v + bias[col];
          ((unsigned short*)Cout)[idx] =
              f2h(0.5f * xx * (1.0f + erff(xx * 0.70710678118654752f)));
        } else {
          ((float*)Cout)[idx] = res[idx] + v + bias[col];
        }
      }
    }
  }
}

// ============================ Flash attention ==============================
// (round-2 known-good version, verbatim) qkv f16 [4096][3072]. S^T = K Q^T,
// online softmax of unscaled logits, O^T = V^T P^T, output *8.
__global__ __launch_bounds__(256) void attn_kernel(
    const unsigned short* __restrict__ qkv, unsigned short* __restrict__ obuf) {
  constexpr int P = 72;  // LDS row pitch (f16 elems), 144B = 9*16B
  __shared__ unsigned short Qs[64 * P], Ks[64 * P], Vs[64 * P];
  const int tid = threadIdx.x;
  const int w = tid >> 6, lane = tid & 63;
  const int g = lane >> 4, lm = lane & 15;
  const int qbase = blockIdx.x * 64, h = blockIdx.y, b = blockIdx.z;
  const size_t rowbase = (size_t)b * 2048;

  // stage Q tile: 64 rows x 64 cols
#pragma unroll
  for (int s = 0; s < 2; ++s) {
    const int c = s * 256 + tid;
    const int r = c >> 3, cc = c & 7;
    *(uint4*)&Qs[r * P + cc * 8] =
        *(const uint4*)(qkv + (rowbase + qbase + r) * 3072 + h * 64 + cc * 8);
  }

  float mrun = -1e30f, lrun = 0.0f;
  f32x4 accO[4] = {};  // O^T dh-tiles

  for (int kv0 = 0; kv0 < 2048; kv0 += 64) {
    __syncthreads();
#pragma unroll
    for (int s = 0; s < 2; ++s) {
      const int c = s * 256 + tid;
      const int r = c >> 3, cc = c & 7;
      const size_t grow = (rowbase + kv0 + r) * 3072 + h * 64 + cc * 8;
      *(uint4*)&Ks[r * P + cc * 8] = *(const uint4*)(qkv + 1024 + grow);
      *(uint4*)&Vs[r * P + cc * 8] = *(const uint4*)(qkv + 2048 + grow);
    }
    __syncthreads();

    // S^T tiles: rows kv (4 subtiles of 16), cols q (this wave's 16 rows)
    f32x4 sf[4];
#pragma unroll
    for (int i = 0; i < 4; ++i) sf[i] = f32x4{0.f, 0.f, 0.f, 0.f};
#pragma unroll
    for (int step = 0; step < 2; ++step) {
      const short8 qf = *(const short8*)&Qs[(w * 16 + lm) * P + step * 32 + g * 8];
#pragma unroll
      for (int i = 0; i < 4; ++i) {
        const short8 kf = *(const short8*)&Ks[(i * 16 + lm) * P + step * 32 + g * 8];
        sf[i] = MFMA(kf, qf, sf[i]);
      }
    }

    // online softmax per q (= lm); lanes lm, lm+16, lm+32, lm+48 share a row
    float tmax = -1e30f;
#pragma unroll
    for (int i = 0; i < 4; ++i)
#pragma unroll
      for (int r = 0; r < 4; ++r) tmax = fmaxf(tmax, sf[i][r]);
    tmax = fmaxf(tmax, __shfl_xor(tmax, 16, 64));
    tmax = fmaxf(tmax, __shfl_xor(tmax, 32, 64));
    const float mnew = fmaxf(mrun, tmax);
    const float scale = __expf(mrun - mnew);
    float p[4][4];
    float psum = 0.0f;
#pragma unroll
    for (int i = 0; i < 4; ++i)
#pragma unroll
      for (int r = 0; r < 4; ++r) {
        p[i][r] = __expf(sf[i][r] - mnew);
        psum += p[i][r];
      }
    psum += __shfl_xor(psum, 16, 64);
    psum += __shfl_xor(psum, 32, 64);
    lrun = lrun * scale + psum;
    mrun = mnew;
#pragma unroll
    for (int t = 0; t < 4; ++t) accO[t] = accO[t] * scale;

    // pack P -> f16 frags (kv slot mapping mirrors V^T A-operand)
    short8 pb[2];
#pragma unroll
    for (int blk = 0; blk < 2; ++blk)
#pragma unroll
      for (int j = 0; j < 8; ++j)
        pb[blk][j] = (short)f2h(p[2 * blk + (j >> 2)][j & 3]);

    // O^T += V^T @ P^T
#pragma unroll
    for (int blk = 0; blk < 2; ++blk) {
#pragma unroll
      for (int t = 0; t < 4; ++t) {
        short8 vf;
#pragma unroll
        for (int j = 0; j < 8; ++j) {
          const int kvl = 32 * blk + ((j >> 2) << 4) + 4 * g + (j & 3);
          vf[j] = (short)Vs[kvl * P + t * 16 + lm];
        }
        accO[t] = MFMA(vf, pb[blk], accO[t]);
      }
    }
  }

  // epilogue: divide by row-sum, multiply by 1/SCALE = 8
  const float inv = 8.0f / lrun;
  const size_t orow = rowbase + qbase + w * 16 + lm;
#pragma unroll
  for (int t = 0; t < 4; ++t)
#pragma unroll
    for (int r = 0; r < 4; ++r) {
      const int col = h * 64 + t * 16 + g * 4 + r;
      obuf[orow * 1024 + col] = f2h(accO[t][r] * inv);
    }
}

// ================================ driver ===================================
extern "C" void kernel_launch(void* const* d_in, const int* in_sizes, int n_in,
                              void* d_out, int out_size, void* d_ws, size_t ws_size,
                              hipStream_t stream) {
  const float* x     = (const float*)d_in[0];
  const float* ln1_g = (const float*)d_in[1];
  const float* ln1_b = (const float*)d_in[2];
  const float* w_qkv = (const float*)d_in[3];
  const float* w_out = (const float*)d_in[4];
  const float* b_out = (const float*)d_in[5];
  const float* ln2_g = (const float*)d_in[6];
  const float* ln2_b = (const float*)d_in[7];
  const float* w1    = (const float*)d_in[8];
  const float* b1    = (const float*)d_in[9];
  const float* w2    = (const float*)d_in[10];
  const float* b2    = (const float*)d_in[11];
  float* h = (float*)d_out;  // residual stream lives in d_out

  char* ws = (char*)d_ws;
  const size_t MB = 1u << 20;
  unsigned short* xn   = (unsigned short*)(ws);             //  8 MiB
  unsigned short* ob   = (unsigned short*)(ws + 8 * MB);    //  8 MiB
  unsigned short* qkvb = (unsigned short*)(ws + 16 * MB);   // 24 MiB
  unsigned short* mid  = (unsigned short*)(ws + 40 * MB);   // 32 MiB
  unsigned short* wt   = (unsigned short*)(ws + 72 * MB);   //  8 MiB

  hipError_t e0 = hipMemcpyAsync(h, x, (size_t)4096 * 1024 * sizeof(float),
                                 hipMemcpyDeviceToDevice, stream);
  (void)e0;

  const dim3 tb(32, 8);
  for (int L = 0; L < 6; ++L) {
    const float* Lg1 = ln1_g + L * 1024;
    const float* Lb1 = ln1_b + L * 1024;
    const float* Lwq = w_qkv + (size_t)L * 1024 * 3072;
    const float* Lwo = w_out + (size_t)L * 1024 * 1024;
    const float* Lbo = b_out + L * 1024;
    const float* Lg2 = ln2_g + L * 1024;
    const float* Lb2 = ln2_b + L * 1024;
    const float* Lw1 = w1 + (size_t)L * 1024 * 4096;
    const float* Lb1m = b1 + L * 4096;
    const float* Lw2 = w2 + (size_t)L * 4096 * 1024;
    const float* Lb2m = b2 + L * 1024;

    // --- attention path ---
    ln_f16_kernel<<<4096, 256, 0, stream>>>(h, Lg1, Lb1, xn);
    transpose_f16_kernel<<<dim3(96, 32), tb, 0, stream>>>(Lwq, wt, 1024, 3072);
    gemm_f16_kernel<128, 0><<<dim3(24, 32), 256, 0, stream>>>(
        xn, wt, qkvb, nullptr, nullptr, 4096, 3072, 1024);
    attn_kernel<<<dim3(32, 16, 2), 256, 0, stream>>>(qkvb, ob);
    transpose_f16_kernel<<<dim3(32, 32), tb, 0, stream>>>(Lwo, wt, 1024, 1024);
    gemm_f16_kernel<64, 2><<<dim3(8, 64), 256, 0, stream>>>(
        ob, wt, h, Lbo, h, 4096, 1024, 1024);

    // --- MLP path ---
    ln_f16_kernel<<<4096, 256, 0, stream>>>(h, Lg2, Lb2, xn);
    transpose_f16_kernel<<<dim3(128, 32), tb, 0, stream>>>(Lw1, wt, 1024, 4096);
    gemm_f16_kernel<128, 1><<<dim3(32, 32), 256, 0, stream>>>(
        xn, wt, mid, Lb1m, nullptr, 4096, 4096, 1024);
    transpose_f16_kernel<<<dim3(32, 128), tb, 0, stream>>>(Lw2, wt, 4096, 1024);
    gemm_f16_kernel<64, 2><<<dim3(8, 64), 256, 0, stream>>>(
        mid, wt, h, Lb2m, h, 4096, 1024, 4096);
  }
  (void)in_sizes; (void)n_in; (void)out_size; (void)ws_size;
}

// Round 7
// 1829.749 us; speedup vs baseline: 1.2361x; 1.0130x over previous
//
#include <hip/hip_runtime.h>
#include <cstdint>

typedef __attribute__((ext_vector_type(4))) float f32x4;
typedef __attribute__((ext_vector_type(8))) short short8;
typedef __attribute__((ext_vector_type(4))) short short4v;
typedef _Float16 half8v __attribute__((ext_vector_type(8)));

// f32 -> f16 bits (RTE via hardware cvt)
__device__ __forceinline__ unsigned short f2h(float x) {
  _Float16 h = (_Float16)x;
  return __builtin_bit_cast(unsigned short, h);
}
// packed f32x2 -> f16x2 (v_cvt_pkrtz_f16_f32); builtin returns __fp16x2
__device__ __forceinline__ unsigned int pk2(float a, float b) {
  auto h = __builtin_amdgcn_cvt_pkrtz(a, b);
  return __builtin_bit_cast(unsigned int, h);
}

// ---- MFMA wrapper: tolerant of short8-vs-half8 builtin signatures ----
template <typename V>
__device__ __forceinline__ auto mfma_impl(V a, V b, f32x4 c, int)
    -> decltype(__builtin_amdgcn_mfma_f32_16x16x32_f16(a, b, c, 0, 0, 0)) {
  return __builtin_amdgcn_mfma_f32_16x16x32_f16(a, b, c, 0, 0, 0);
}
template <typename V>
__device__ __forceinline__ f32x4 mfma_impl(V a, V b, f32x4 c, long) {
  return __builtin_amdgcn_mfma_f32_16x16x32_f16(
      __builtin_bit_cast(half8v, a), __builtin_bit_cast(half8v, b), c, 0, 0, 0);
}
__device__ __forceinline__ f32x4 MFMA(short8 a, short8 b, f32x4 c) {
  return mfma_impl(a, b, c, 0);
}

// ---- async global->LDS, 16B per lane, LDS dest MUST be wave-uniform ----
__device__ __forceinline__ void load_lds16(const void* g, void* l) {
  __builtin_amdgcn_global_load_lds(
      (__attribute__((address_space(1))) void*)(uintptr_t)g,
      (__attribute__((address_space(3))) void*)l, 16, 0, 0);
}

// ============================ LayerNorm -> f16 =============================
__global__ __launch_bounds__(256) void ln_f16_kernel(
    const float* __restrict__ X, const float* __restrict__ gam,
    const float* __restrict__ bet, unsigned short* __restrict__ Y) {
  __shared__ float red[8];
  const int row = blockIdx.x, t = threadIdx.x;
  const float4 v = ((const float4*)(X + (size_t)row * 1024))[t];
  float s = v.x + v.y + v.z + v.w;
#pragma unroll
  for (int o = 32; o >= 1; o >>= 1) s += __shfl_xor(s, o, 64);
  if ((t & 63) == 0) red[t >> 6] = s;
  __syncthreads();
  const float mean = (red[0] + red[1] + red[2] + red[3]) * (1.0f / 1024.0f);
  const float dx = v.x - mean, dy = v.y - mean, dz = v.z - mean, dw = v.w - mean;
  float ss = dx * dx + dy * dy + dz * dz + dw * dw;
#pragma unroll
  for (int o = 32; o >= 1; o >>= 1) ss += __shfl_xor(ss, o, 64);
  if ((t & 63) == 0) red[4 + (t >> 6)] = ss;
  __syncthreads();
  const float var = (red[4] + red[5] + red[6] + red[7]) * (1.0f / 1024.0f);
  const float rstd = rsqrtf(var + 1e-5f);
  const float4 gg = ((const float4*)gam)[t];
  const float4 bb = ((const float4*)bet)[t];
  ushort4 o4;
  o4.x = f2h(dx * rstd * gg.x + bb.x);
  o4.y = f2h(dy * rstd * gg.y + bb.y);
  o4.z = f2h(dz * rstd * gg.z + bb.z);
  o4.w = f2h(dw * rstd * gg.w + bb.w);
  ((ushort4*)(Y + (size_t)row * 1024))[t] = o4;
}

// ================= transpose + fp32->f16 convert: W[K][N] -> WT[N][K] ======
__global__ __launch_bounds__(256) void transpose_f16_kernel(
    const float* __restrict__ W, unsigned short* __restrict__ WT, int K, int N) {
  __shared__ float t[32][33];
  const int n0 = blockIdx.x * 32, k0 = blockIdx.y * 32;
  const int tx = threadIdx.x, ty = threadIdx.y;
#pragma unroll
  for (int i = 0; i < 4; ++i)
    t[ty + 8 * i][tx] = W[(size_t)(k0 + ty + 8 * i) * N + n0 + tx];
  __syncthreads();
#pragma unroll
  for (int i = 0; i < 4; ++i)
    WT[(size_t)(n0 + ty + 8 * i) * K + k0 + tx] = f2h(t[tx][ty + 8 * i]);
}

// ============================ GEMM (f16 MFMA) ==============================
// C[M][N] = A[M][K] @ B[K][N] with BT[N][K]. BK=64, double-buffered LDS,
// 2-phase pipeline (stage next || compute current), XOR-swizzled LDS layout
// (pre-swizzled per-lane global SOURCE; wave-uniform linear LDS dest;
// swizzled reads). EPI 0: f16. EPI 1: f16 gelu(acc+bias). EPI 2: f32 res+acc+bias.
template <int BM, int EPI>
__global__ __launch_bounds__(256, BM == 64 ? 3 : 2) void gemm_f16_kernel(
    const unsigned short* __restrict__ A, const unsigned short* __restrict__ BT,
    void* Cout, const float* __restrict__ bias, const float* __restrict__ res,
    int M, int N, int K) {
  constexpr int BN = 128, BK = 64;
  constexpr int MR = BM / 32;             // frag-rows per wave (wave = BM/2 x 64)
  constexpr int ACH = BM * BK / 8;        // 16B chunks of A per K-step
  constexpr int BCH = BN * BK / 8;
  __shared__ alignas(16) unsigned short a_sh[2][BM * BK];
  __shared__ alignas(16) unsigned short b_sh[2][BN * BK];
  const int tid = threadIdx.x;
  const int w = tid >> 6, lane = tid & 63, g = lane >> 4, lm = lane & 15;
  const int m0 = blockIdx.y * BM, n0 = blockIdx.x * BN;
  const int wm = (w >> 1) * (BM / 2), wn = (w & 1) * 64;
  f32x4 acc[MR][4] = {};
  const int nsteps = K >> 6;

  auto stage = [&](int buf, int kk) {
#pragma unroll
    for (int c0 = 0; c0 < ACH; c0 += 256) {
      const int c = c0 + tid, row = c >> 3;
      const int sc = (c & 7) ^ (row & 7);   // pre-swizzled per-lane source
      const int cb = c0 + (tid & 192);      // wave-uniform dest chunk base
      load_lds16(A + (size_t)(m0 + row) * K + kk + sc * 8, &a_sh[buf][cb * 8]);
    }
#pragma unroll
    for (int c0 = 0; c0 < BCH; c0 += 256) {
      const int c = c0 + tid, row = c >> 3;
      const int sc = (c & 7) ^ (row & 7);
      const int cb = c0 + (tid & 192);
      load_lds16(BT + (size_t)(n0 + row) * K + kk + sc * 8, &b_sh[buf][cb * 8]);
    }
  };

  stage(0, 0);
  __syncthreads();
  int cur = 0;
  for (int step = 0; step < nsteps; ++step) {
    if (step + 1 < nsteps) stage(cur ^ 1, (step + 1) * BK);
#pragma unroll
    for (int kc = 0; kc < 2; ++kc) {
      short8 af[MR], bfr[4];
#pragma unroll
      for (int i = 0; i < MR; ++i) {
        const int r = wm + i * 16 + lm;
        af[i] = *(const short8*)&a_sh[cur][r * 64 + (((kc << 2) | g) ^ (r & 7)) * 8];
      }
#pragma unroll
      for (int j = 0; j < 4; ++j) {
        const int r = wn + j * 16 + lm;
        bfr[j] = *(const short8*)&b_sh[cur][r * 64 + (((kc << 2) | g) ^ (r & 7)) * 8];
      }
#pragma unroll
      for (int i = 0; i < MR; ++i)
#pragma unroll
        for (int j = 0; j < 4; ++j)
          acc[i][j] = MFMA(af[i], bfr[j], acc[i][j]);
    }
    if (step + 1 < nsteps) {
      __syncthreads();  // drains prefetch vmcnt + LDS reads; swap buffers
      cur ^= 1;
    }
  }

#pragma unroll
  for (int i = 0; i < MR; ++i) {
    const int row = m0 + wm + i * 16 + g * 4;
#pragma unroll
    for (int j = 0; j < 4; ++j) {
      const int col = n0 + wn + j * 16 + lm;
#pragma unroll
      for (int r = 0; r < 4; ++r) {
        const float v = acc[i][j][r];
        const size_t idx = (size_t)(row + r) * N + col;
        if (EPI == 0) {
          ((unsigned short*)Cout)[idx] = f2h(v);
        } else if (EPI == 1) {
          const float xx = v + bias[col];
          ((unsigned short*)Cout)[idx] =
              f2h(0.5f * xx * (1.0f + erff(xx * 0.70710678118654752f)));
        } else {
          ((float*)Cout)[idx] = res[idx] + v + bias[col];
        }
      }
    }
  }
}

// ============================ Flash attention ==============================
// qkv f16 [4096][3072]. S^T = K Q^T, online softmax of unscaled logits,
// O^T = V^T P^T, output *8. V staged TRANSPOSED in LDS (VsT[d][kv], pitch 68)
// so the PV A-fragment gather vf[j] = V[32blk+16(j>>2)+4g+(j&3)][16t+lm] is
// two aligned ds_read_b64 per (blk,t) instead of 8 scalar ds_read_u16.
// K/V global loads prefetched to regs (async-stage under compute).
__global__ __launch_bounds__(256) void attn_kernel(
    const unsigned short* __restrict__ qkv, unsigned short* __restrict__ obuf) {
  constexpr int PK = 72;   // K/Q row pitch (f16 elems)
  constexpr int PV = 68;   // V^T row pitch: 64 kv + 4 pad (136B, 8B-aligned rows)
  __shared__ alignas(16) unsigned short Qs[64 * PK];
  __shared__ alignas(16) unsigned short Ks[64 * PK];
  __shared__ alignas(16) unsigned short VsT[64 * PV];  // VsT[d][kv]
  const int tid = threadIdx.x;
  const int w = tid >> 6, lane = tid & 63, g = lane >> 4, lm = lane & 15;
  const int qbase = blockIdx.x * 64, h = blockIdx.y, b = blockIdx.z;
  const size_t rowbase = (size_t)b * 2048;
  const int r0 = tid >> 3, cc = tid & 7;  // r0 in [0,32), cc in [0,8)

  // stage Q tile (64 x 64)
  const unsigned short* qptr = qkv + (rowbase + qbase + r0) * 3072 + h * 64 + cc * 8;
#pragma unroll
  for (int s = 0; s < 2; ++s)
    *(uint4*)&Qs[(s * 32 + r0) * PK + cc * 8] = *(const uint4*)(qptr + (size_t)s * 32 * 3072);

  // prefetch K/V tile 0 into registers (thread owns K/V row r0+32s, d=cc*8..+7)
  const unsigned short* kvptr = qkv + (rowbase + r0) * 3072 + h * 64 + cc * 8;
  uint4 kreg[2], vreg[2];
#pragma unroll
  for (int s = 0; s < 2; ++s) {
    kreg[s] = *(const uint4*)(kvptr + 1024 + (size_t)s * 32 * 3072);
    vreg[s] = *(const uint4*)(kvptr + 2048 + (size_t)s * 32 * 3072);
  }
  __syncthreads();  // Q visible
  short8 qf[2];
#pragma unroll
  for (int s2 = 0; s2 < 2; ++s2)
    qf[s2] = *(const short8*)&Qs[(w * 16 + lm) * PK + s2 * 32 + g * 8];

  float mrun = -1e30f, lrun = 0.0f;
  f32x4 accO[4] = {};
  const int kdst = r0 * PK + cc * 8;

  for (int kv0 = 0; kv0 < 2048; kv0 += 64) {
    __syncthreads();  // all waves done reading previous K/V
#pragma unroll
    for (int s = 0; s < 2; ++s) {
      *(uint4*)&Ks[kdst + s * 32 * PK] = kreg[s];
      // V transposed store: elem e of vreg[s] is V[kv=32s+r0][d=cc*8+e]
      const unsigned* vu = (const unsigned*)&vreg[s];
#pragma unroll
      for (int e2 = 0; e2 < 4; ++e2) {
        const unsigned v2 = vu[e2];
        VsT[(cc * 8 + 2 * e2) * PV + 32 * s + r0] = (unsigned short)(v2 & 0xffffu);
        VsT[(cc * 8 + 2 * e2 + 1) * PV + 32 * s + r0] = (unsigned short)(v2 >> 16);
      }
    }
    __syncthreads();
    if (kv0 + 64 < 2048) {  // issue next tile's loads; land under compute
      const unsigned short* np = kvptr + (size_t)(kv0 + 64) * 3072;
#pragma unroll
      for (int s = 0; s < 2; ++s) {
        kreg[s] = *(const uint4*)(np + 1024 + (size_t)s * 32 * 3072);
        vreg[s] = *(const uint4*)(np + 2048 + (size_t)s * 32 * 3072);
      }
    }

    // S^T = K Q^T (4 kv-subtiles x this wave's 16 q-rows)
    f32x4 sf[4] = {};
#pragma unroll
    for (int s2 = 0; s2 < 2; ++s2)
#pragma unroll
      for (int i = 0; i < 4; ++i) {
        const short8 kf = *(const short8*)&Ks[(i * 16 + lm) * PK + s2 * 32 + g * 8];
        sf[i] = MFMA(kf, qf[s2], sf[i]);
      }

    // online softmax per q-row (lanes lm, lm+16, lm+32, lm+48 share a row)
    float tmax = -1e30f;
#pragma unroll
    for (int i = 0; i < 4; ++i)
#pragma unroll
      for (int r = 0; r < 4; ++r) tmax = fmaxf(tmax, sf[i][r]);
    tmax = fmaxf(tmax, __shfl_xor(tmax, 16, 64));
    tmax = fmaxf(tmax, __shfl_xor(tmax, 32, 64));
    const float mnew = fmaxf(mrun, tmax);
    const float scale = __expf(mrun - mnew);
    float p[4][4];
    float psum = 0.0f;
#pragma unroll
    for (int i = 0; i < 4; ++i)
#pragma unroll
      for (int r = 0; r < 4; ++r) {
        p[i][r] = __expf(sf[i][r] - mnew);
        psum += p[i][r];
      }
    psum += __shfl_xor(psum, 16, 64);
    psum += __shfl_xor(psum, 32, 64);
    lrun = lrun * scale + psum;
    mrun = mnew;
#pragma unroll
    for (int t = 0; t < 4; ++t) accO[t] = accO[t] * scale;

    // pack P -> f16 fragments (slot j = p[2blk+(j>>2)][j&3])
    uint4 pbu[2];
#pragma unroll
    for (int blk = 0; blk < 2; ++blk) {
      pbu[blk].x = pk2(p[2 * blk][0], p[2 * blk][1]);
      pbu[blk].y = pk2(p[2 * blk][2], p[2 * blk][3]);
      pbu[blk].z = pk2(p[2 * blk + 1][0], p[2 * blk + 1][1]);
      pbu[blk].w = pk2(p[2 * blk + 1][2], p[2 * blk + 1][3]);
    }

    // O^T += V^T @ P^T ; V fragments via two ds_read_b64 per (blk,t)
#pragma unroll
    for (int blk = 0; blk < 2; ++blk) {
      const short8 pbv = __builtin_bit_cast(short8, pbu[blk]);
#pragma unroll
      for (int t = 0; t < 4; ++t) {
        const int base = (16 * t + lm) * PV + 32 * blk + 4 * g;
        const short4v vlo = *(const short4v*)&VsT[base];
        const short4v vhi = *(const short4v*)&VsT[base + 16];
        const short8 vf = {vlo[0], vlo[1], vlo[2], vlo[3],
                           vhi[0], vhi[1], vhi[2], vhi[3]};
        accO[t] = MFMA(vf, pbv, accO[t]);
      }
    }
  }

  // epilogue: divide by row-sum, multiply by 1/SCALE = 8
  const float inv = 8.0f / lrun;
  const size_t orow = rowbase + qbase + w * 16 + lm;
#pragma unroll
  for (int t = 0; t < 4; ++t)
#pragma unroll
    for (int r = 0; r < 4; ++r) {
      const int col = h * 64 + t * 16 + g * 4 + r;
      obuf[orow * 1024 + col] = f2h(accO[t][r] * inv);
    }
}

// ================================ driver ===================================
extern "C" void kernel_launch(void* const* d_in, const int* in_sizes, int n_in,
                              void* d_out, int out_size, void* d_ws, size_t ws_size,
                              hipStream_t stream) {
  const float* x     = (const float*)d_in[0];
  const float* ln1_g = (const float*)d_in[1];
  const float* ln1_b = (const float*)d_in[2];
  const float* w_qkv = (const float*)d_in[3];
  const float* w_out = (const float*)d_in[4];
  const float* b_out = (const float*)d_in[5];
  const float* ln2_g = (const float*)d_in[6];
  const float* ln2_b = (const float*)d_in[7];
  const float* w1    = (const float*)d_in[8];
  const float* b1    = (const float*)d_in[9];
  const float* w2    = (const float*)d_in[10];
  const float* b2    = (const float*)d_in[11];
  float* h = (float*)d_out;  // residual stream lives in d_out

  char* ws = (char*)d_ws;
  const size_t MB = 1u << 20;
  unsigned short* xn   = (unsigned short*)(ws);             //  8 MiB
  unsigned short* ob   = (unsigned short*)(ws + 8 * MB);    //  8 MiB
  unsigned short* qkvb = (unsigned short*)(ws + 16 * MB);   // 24 MiB
  unsigned short* mid  = (unsigned short*)(ws + 40 * MB);   // 32 MiB
  unsigned short* wt   = (unsigned short*)(ws + 72 * MB);   //  8 MiB

  hipError_t e0 = hipMemcpyAsync(h, x, (size_t)4096 * 1024 * sizeof(float),
                                 hipMemcpyDeviceToDevice, stream);
  (void)e0;

  const dim3 tb(32, 8);
  for (int L = 0; L < 6; ++L) {
    const float* Lg1 = ln1_g + L * 1024;
    const float* Lb1 = ln1_b + L * 1024;
    const float* Lwq = w_qkv + (size_t)L * 1024 * 3072;
    const float* Lwo = w_out + (size_t)L * 1024 * 1024;
    const float* Lbo = b_out + L * 1024;
    const float* Lg2 = ln2_g + L * 1024;
    const float* Lb2 = ln2_b + L * 1024;
    const float* Lw1 = w1 + (size_t)L * 1024 * 4096;
    const float* Lb1m = b1 + L * 4096;
    const float* Lw2 = w2 + (size_t)L * 4096 * 1024;
    const float* Lb2m = b2 + L * 1024;

    // --- attention path ---
    ln_f16_kernel<<<4096, 256, 0, stream>>>(h, Lg1, Lb1, xn);
    transpose_f16_kernel<<<dim3(96, 32), tb, 0, stream>>>(Lwq, wt, 1024, 3072);
    gemm_f16_kernel<128, 0><<<dim3(24, 32), 256, 0, stream>>>(
        xn, wt, qkvb, nullptr, nullptr, 4096, 3072, 1024);
    attn_kernel<<<dim3(32, 16, 2), 256, 0, stream>>>(qkvb, ob);
    transpose_f16_kernel<<<dim3(32, 32), tb, 0, stream>>>(Lwo, wt, 1024, 1024);
    gemm_f16_kernel<64, 2><<<dim3(8, 64), 256, 0, stream>>>(
        ob, wt, h, Lbo, h, 4096, 1024, 1024);

    // --- MLP path ---
    ln_f16_kernel<<<4096, 256, 0, stream>>>(h, Lg2, Lb2, xn);
    transpose_f16_kernel<<<dim3(128, 32), tb, 0, stream>>>(Lw1, wt, 1024, 4096);
    gemm_f16_kernel<128, 1><<<dim3(32, 32), 256, 0, stream>>>(
        xn, wt, mid, Lb1m, nullptr, 4096, 4096, 1024);
    transpose_f16_kernel<<<dim3(32, 128), tb, 0, stream>>>(Lw2, wt, 4096, 1024);
    gemm_f16_kernel<64, 2><<<dim3(8, 64), 256, 0, stream>>>(
        mid, wt, h, Lb2m, h, 4096, 1024, 4096);
  }
  (void)in_sizes; (void)n_in; (void)out_size; (void)ws_size;
}